// Round 7
// baseline (126.754 us; speedup 1.0000x reference)
//
#include <hip/hip_runtime.h>
#include <math.h>

#define NB 37
#define BB 4
#define FF 1025
#define TT 2048
#define EE 128
#define DD 260
#define EPSF 1e-5f
#define CHS 9           // max K chunks of 32 (Kpad<=288)

typedef short s16x8 __attribute__((ext_vector_type(8)));
typedef float f32x4 __attribute__((ext_vector_type(4)));
typedef const unsigned int __attribute__((address_space(1))) gu32;
typedef unsigned int __attribute__((address_space(3))) lu32;

__device__ __forceinline__ unsigned short f2bf(float f) {
    unsigned u = __builtin_bit_cast(unsigned, f);
    unsigned r = (u + 0x7FFFu + ((u >> 16) & 1u)) >> 16;
    return (unsigned short)r;
}

// ---------------------------------------------------------------------------
// Kernel 1: per-band prep (unchanged).
// A[e,k] = gamma[d(k)] * g[e]*v[e,d(k)]/||v[e]||, ATg layout [n][ch][e][32k],
// zero-padded within partial chunks. s1[e]=sum A, s2p[e]=sum beta*W + bias.
// ---------------------------------------------------------------------------
__global__ __launch_bounds__(256) void prep_kernel(
    const float* __restrict__ gamma, const float* __restrict__ beta,
    const float* __restrict__ v, const float* __restrict__ g,
    const float* __restrict__ bias, const int* __restrict__ bwidth,
    unsigned short* __restrict__ ATg, float* __restrict__ s1o, float* __restrict__ s2o)
{
    int bid = blockIdx.x;
    int n   = bid >> 4;
    int eg  = bid & 15;
    int tid = threadIdx.x;
    int el  = tid >> 5;          // 0..7
    int kk  = tid & 31;
    int e   = eg * 8 + el;

    int bw    = bwidth[n];
    int Deff  = 4 * bw;
    int twobw = 2 * bw;
    int nCh   = (Deff + 31) >> 5;

    const float* vp = v + (size_t)(n * EE + e) * DD;

    float sq = 0.f;
    for (int d = kk; d < DD; d += 32) { float val = vp[d]; sq = fmaf(val, val, sq); }
    #pragma unroll
    for (int m = 16; m >= 1; m >>= 1) sq += __shfl_xor(sq, m);

    float rv = g[n * EE + e] * rsqrtf(sq);

    float s1 = 0.f, s2 = 0.f;
    unsigned short* Abase = ATg + (size_t)n * CHS * (EE * 32) + e * 32 + kk;
    for (int ch = 0; ch < nCh; ++ch) {
        int k = ch * 32 + kk;
        float a = 0.f;
        if (k < Deff) {
            int d = (k >= twobw) ? (130 + k - twobw) : k;
            float W = rv * vp[d];
            a = gamma[n * DD + d] * W;
            s1 += a;
            s2 = fmaf(beta[n * DD + d], W, s2);
        }
        Abase[(size_t)ch * (EE * 32)] = f2bf(a);
    }
    #pragma unroll
    for (int m = 16; m >= 1; m >>= 1) { s1 += __shfl_xor(s1, m); s2 += __shfl_xor(s2, m); }
    if (kk == 0) {
        s1o[n * EE + e] = s1;
        s2o[n * EE + e] = s2 + bias[n * EE + e];
    }
}

// ---------------------------------------------------------------------------
// Kernel 2: fused stats + MFMA GEMM. Block = (b, n, 512-t slab); 4 waves
// (2t x 2e of 64x64). Flattened (ts, ch) pipeline: STAGE(next) DMA issued
// before compute(cur), one __syncthreads drain per step. A-operand = W
// (swapped): output row=e (reg-contiguous -> float4 stores), col=t (mean/rs
// consumed in-lane, no broadcast). A fragments: registers for bw<=32 (loaded
// once), per-chunk global loads (issued before DMA; L1-hot across subtiles)
// for bw>=64.
// ---------------------------------------------------------------------------
template <int BW>
__device__ __forceinline__ void run_band(
    const float* __restrict__ x, const unsigned short* __restrict__ ATg,
    const float* __restrict__ s1a, const float* __restrict__ s2a,
    float* __restrict__ out, float* __restrict__ Xs,
    int b, int n, int tslab0, int f0, int tid)
{
    constexpr int  NCH   = (4 * BW + 31) / 32;   // 2,4,8,9
    constexpr bool TAIL  = (BW == 65);
    constexpr bool ARES  = (BW <= 32);
    constexpr int  NPAIR = 2 * BW;
    constexpr int  REMP  = NPAIR - (NCH - 1) * 16;   // 2 for BW=65

    const int lane  = tid & 63;
    const int l15   = lane & 15;
    const int ksub  = lane >> 4;
    const int wv    = tid >> 6;
    const int tband = (wv >> 1) * 64;
    const int ewave = (wv & 1) * 64;

    const s16x8* Ab = reinterpret_cast<const s16x8*>(
        ATg + (size_t)n * CHS * (EE * 32)) + ((ewave + l15) * 4 + ksub);

    // A fragments resident in registers for small/mid bands
    s16x8 afr[ARES ? NCH : 1][4];
    if (ARES) {
        #pragma unroll
        for (int ch = 0; ch < NCH; ++ch)
            #pragma unroll
            for (int ni = 0; ni < 4; ++ni)
                afr[ch][ni] = Ab[ch * 512 + ni * 64];
    }

    const char* xb = (const char*)x + (size_t)(b * 2) * FF * 16384
                   + (size_t)tslab0 * 8 + (size_t)lane * 16;

    auto STAGE = [&](int ts, int ch, int bufOff) {
        #pragma unroll
        for (int j = 0; j < 4; ++j) {
            int p = ch * 16 + wv * 4 + j;
            if (TAIL && p > NPAIR - 1) p = NPAIR - 1;   // clamp; masked in compute
            int c = (p >= BW) ? 1 : 0;
            int row = c * FF + f0 + p - c * BW;
            const char* gsrc = xb + (size_t)row * 16384 + (size_t)ts * 1024;
            __builtin_amdgcn_global_load_lds((gu32*)gsrc,
                (lu32*)(Xs + bufOff + (wv * 4 + j) * 256), 16, 0, 0);
        }
    };

    STAGE(0, 0, 0);
    __syncthreads();                        // buf0 ready (also drains A-reg loads)

    f32x4 acc[4][4];
    #pragma unroll
    for (int mi = 0; mi < 4; ++mi)
        #pragma unroll
        for (int ni = 0; ni < 4; ++ni) acc[mi][ni] = (f32x4){0.f, 0.f, 0.f, 0.f};
    float sA[4] = {0.f, 0.f, 0.f, 0.f}, qA[4] = {0.f, 0.f, 0.f, 0.f};

    int bufOff = 0;
    for (int ts = 0; ts < 4; ++ts) {
        #pragma unroll
        for (int ch = 0; ch < NCH; ++ch) {
            // A fragments first (FIFO: their vmcnt-wait leaves the DMAs in flight)
            s16x8 aw0, aw1, aw2, aw3;
            if (ARES) {
                aw0 = afr[ch][0]; aw1 = afr[ch][1]; aw2 = afr[ch][2]; aw3 = afr[ch][3];
            } else {
                aw0 = Ab[ch * 512];       aw1 = Ab[ch * 512 + 64];
                aw2 = Ab[ch * 512 + 128]; aw3 = Ab[ch * 512 + 192];
            }
            int nbuf = bufOff ^ 4096;
            if (ch + 1 < NCH)      STAGE(ts, ch + 1, nbuf);
            else if (ts + 1 < 4)   STAGE(ts + 1, 0, nbuf);

            const float2* Xp = reinterpret_cast<const float2*>(Xs + bufOff);
            #pragma unroll
            for (int mi = 0; mi < 4; ++mi) {
                float2 vv[4];
                #pragma unroll
                for (int j = 0; j < 4; ++j)
                    vv[j] = Xp[(4 * ksub + j) * 128 + tband + mi * 16 + l15];
                if (TAIL && ch == NCH - 1) {
                    #pragma unroll
                    for (int j = 0; j < 4; ++j)
                        if (4 * ksub + j >= REMP) vv[j] = make_float2(0.f, 0.f);
                }
                float s = 0.f, q = 0.f;
                s16x8 af;
                #pragma unroll
                for (int j = 0; j < 4; ++j) {
                    s += vv[j].x + vv[j].y;
                    q = fmaf(vv[j].x, vv[j].x, q);
                    q = fmaf(vv[j].y, vv[j].y, q);
                    af[2 * j]     = (short)f2bf(vv[j].x);
                    af[2 * j + 1] = (short)f2bf(vv[j].y);
                }
                sA[mi] += s;
                qA[mi] += q;
                acc[mi][0] = __builtin_amdgcn_mfma_f32_16x16x32_bf16(aw0, af, acc[mi][0], 0, 0, 0);
                acc[mi][1] = __builtin_amdgcn_mfma_f32_16x16x32_bf16(aw1, af, acc[mi][1], 0, 0, 0);
                acc[mi][2] = __builtin_amdgcn_mfma_f32_16x16x32_bf16(aw2, af, acc[mi][2], 0, 0, 0);
                acc[mi][3] = __builtin_amdgcn_mfma_f32_16x16x32_bf16(aw3, af, acc[mi][3], 0, 0, 0);
            }
            __syncthreads();               // next buffer ready (DMA drained)
            bufOff ^= 4096;
        }

        // ---- flush t-subtile: stats finalize in-lane, float4 epilogue stores
        constexpr float inv = 1.f / (float)(4 * BW);
        size_t outT = (size_t)(b * NB + n) * TT + tslab0 + ts * 128;
        #pragma unroll
        for (int mi = 0; mi < 4; ++mi) {
            float s = sA[mi], q = qA[mi];
            s += __shfl_xor(s, 16); s += __shfl_xor(s, 32);
            q += __shfl_xor(q, 16); q += __shfl_xor(q, 32);
            float mean = s * inv;
            float rs   = rsqrtf(fmaf(q, inv, -(mean * mean)) + EPSF);
            float* op = out + (outT + tband + mi * 16 + l15) * EE + ewave + ksub * 4;
            #pragma unroll
            for (int ni = 0; ni < 4; ++ni) {
                float4 s1q = *reinterpret_cast<const float4*>(
                    &s1a[n * EE + ewave + ni * 16 + ksub * 4]);
                float4 s2q = *reinterpret_cast<const float4*>(
                    &s2a[n * EE + ewave + ni * 16 + ksub * 4]);
                f32x4 a = acc[mi][ni];
                float4 z;
                z.x = fmaf(rs, a[0] - mean * s1q.x, s2q.x);
                z.y = fmaf(rs, a[1] - mean * s1q.y, s2q.y);
                z.z = fmaf(rs, a[2] - mean * s1q.z, s2q.z);
                z.w = fmaf(rs, a[3] - mean * s1q.w, s2q.w);
                *reinterpret_cast<float4*>(op + ni * 16) = z;
                acc[mi][ni] = (f32x4){0.f, 0.f, 0.f, 0.f};
            }
            sA[mi] = 0.f; qA[mi] = 0.f;
        }
    }
}

__global__ __launch_bounds__(256) void fused_kernel(
    const float* __restrict__ x, const int* __restrict__ bstart,
    const int* __restrict__ bwidth,
    const unsigned short* __restrict__ ATg, const float* __restrict__ s1a,
    const float* __restrict__ s2a, float* __restrict__ out)
{
    __shared__ __align__(16) float Xs[2 * 4096];   // 2 x 16KB x-chunk buffers

    int bid = blockIdx.x;
    int r   = bid % NB;
    int n   = NB - 1 - r;            // big bands first
    int q2  = bid / NB;
    int tslab0 = (q2 & 3) * 512;
    int b   = q2 >> 2;
    int f0  = bstart[n];
    int bw  = bwidth[n];
    int tid = threadIdx.x;

    if (bw == 16)
        run_band<16>(x, ATg, s1a, s2a, out, Xs, b, n, tslab0, f0, tid);
    else if (bw == 32)
        run_band<32>(x, ATg, s1a, s2a, out, Xs, b, n, tslab0, f0, tid);
    else if (bw == 64)
        run_band<64>(x, ATg, s1a, s2a, out, Xs, b, n, tslab0, f0, tid);
    else
        run_band<65>(x, ATg, s1a, s2a, out, Xs, b, n, tslab0, f0, tid);
}

// ---------------------------------------------------------------------------
extern "C" void kernel_launch(void* const* d_in, const int* in_sizes, int n_in,
                              void* d_out, int out_size, void* d_ws, size_t ws_size,
                              hipStream_t stream)
{
    const float* x      = (const float*)d_in[0];
    const float* gamma  = (const float*)d_in[1];
    const float* beta   = (const float*)d_in[2];
    const float* v      = (const float*)d_in[3];
    const float* g      = (const float*)d_in[4];
    const float* bias   = (const float*)d_in[5];
    const int*   bstart = (const int*)d_in[6];
    const int*   bwidth = (const int*)d_in[7];
    float* out = (float*)d_out;

    unsigned short* ATg = (unsigned short*)d_ws;                 // 37*9*128*32 bf16
    float* s1  = (float*)(ATg + (size_t)NB * CHS * EE * 32);     // 37*128 f32
    float* s2p = s1 + NB * EE;                                   // 37*128 f32

    prep_kernel<<<NB * 16, 256, 0, stream>>>(gamma, beta, v, g, bias, bwidth, ATg, s1, s2p);
    fused_kernel<<<BB * NB * 4, 256, 0, stream>>>(x, bstart, bwidth, ATg, s1, s2p, out);
}

// Round 8
// 80.167 us; speedup vs baseline: 1.5811x; 1.5811x over previous
//
#include <hip/hip_runtime.h>
#include <hip/hip_bf16.h>
#include <math.h>

#define NB 37
#define BB 4
#define CC 2
#define FF 1025
#define TT 2048
#define EE 128
#define DD 260
#define EPSF 1e-5f
#define CHS 9           // max K chunks of 32 (Kpad<=288)

typedef short s16x8 __attribute__((ext_vector_type(8)));
typedef float f32x4 __attribute__((ext_vector_type(4)));
typedef const unsigned int __attribute__((address_space(1))) gu32;
typedef unsigned int __attribute__((address_space(3))) lu32;

__device__ __forceinline__ unsigned short f2bf(float f) {
    unsigned u = __builtin_bit_cast(unsigned, f);
    unsigned r = (u + 0x7FFFu + ((u >> 16) & 1u)) >> 16;
    return (unsigned short)r;
}

// ---------------------------------------------------------------------------
// Kernel 1: per-band prep (unchanged).
// A[e,k] = gamma[d(k)] * g[e]*v[e,d(k)]/||v[e]||, ATg layout [n][ch][e][32k],
// zero-padded within partial chunks. s1[e]=sum A, s2p[e]=sum beta*W + bias.
// ---------------------------------------------------------------------------
__global__ __launch_bounds__(256) void prep_kernel(
    const float* __restrict__ gamma, const float* __restrict__ beta,
    const float* __restrict__ v, const float* __restrict__ g,
    const float* __restrict__ bias, const int* __restrict__ bwidth,
    unsigned short* __restrict__ ATg, float* __restrict__ s1o, float* __restrict__ s2o)
{
    int bid = blockIdx.x;
    int n   = bid >> 4;
    int eg  = bid & 15;
    int tid = threadIdx.x;
    int el  = tid >> 5;          // 0..7
    int kk  = tid & 31;
    int e   = eg * 8 + el;

    int bw    = bwidth[n];
    int Deff  = 4 * bw;
    int twobw = 2 * bw;
    int nCh   = (Deff + 31) >> 5;

    const float* vp = v + (size_t)(n * EE + e) * DD;

    float sq = 0.f;
    for (int d = kk; d < DD; d += 32) { float val = vp[d]; sq = fmaf(val, val, sq); }
    #pragma unroll
    for (int m = 16; m >= 1; m >>= 1) sq += __shfl_xor(sq, m);

    float rv = g[n * EE + e] * rsqrtf(sq);

    float s1 = 0.f, s2 = 0.f;
    unsigned short* Abase = ATg + (size_t)n * CHS * (EE * 32) + e * 32 + kk;
    for (int ch = 0; ch < nCh; ++ch) {
        int k = ch * 32 + kk;
        float a = 0.f;
        if (k < Deff) {
            int d = (k >= twobw) ? (130 + k - twobw) : k;
            float W = rv * vp[d];
            a = gamma[n * DD + d] * W;
            s1 += a;
            s2 = fmaf(beta[n * DD + d], W, s2);
        }
        Abase[(size_t)ch * (EE * 32)] = f2bf(a);
    }
    #pragma unroll
    for (int m = 16; m >= 1; m >>= 1) { s1 += __shfl_xor(s1, m); s2 += __shfl_xor(s2, m); }
    if (kk == 0) {
        s1o[n * EE + e] = s1;
        s2o[n * EE + e] = s2 + bias[n * EE + e];
    }
}

// ---------------------------------------------------------------------------
// Kernel 2: fused stats + MFMA GEMM with global_load_lds staging and a
// counted-vmcnt 3-buffer pipeline (2 chunks in flight across raw barriers).
// Block = 128t x 128e (4 waves of 64t x 64e). Per 32-k chunk: 16 pair-rows of
// 1024B DMA'd to LDS (wave wv stages rows 4wv..4wv+3). Iteration ch:
//   s_waitcnt vmcnt(4)  (ch's DMAs done; ch+1's stay in flight)
//   s_barrier + sched_barrier(0)
//   A-frag loads (auto-wait later = vmcnt(4), leaves new DMAs in flight)
//   STAGE(ch+2) -> buf[(ch+2)%3]   (safe: all waves past compute(ch-1))
//   compute(buf[ch%3])
// ---------------------------------------------------------------------------
__global__ __launch_bounds__(256) void fused_kernel(
    const float* __restrict__ x, const int* __restrict__ bstart,
    const int* __restrict__ bwidth,
    const unsigned short* __restrict__ ATg, const float* __restrict__ s1a,
    const float* __restrict__ s2a, float* __restrict__ out)
{
    int bid  = blockIdx.x;
    int n    = bid % NB;                // fastest -> uniform band mix over time
    int rest = bid / NB;
    int tt   = rest & 15;               // T/128 = 16
    int b    = rest >> 4;
    int t0   = tt * 128;
    int f0   = bstart[n];
    int bw   = bwidth[n];
    int nPairs = 2 * bw;
    int Deff   = 4 * bw;
    int nChF   = Deff >> 5;             // 2,4,8,8
    int remP   = nPairs - nChF * 16;    // 2 for band 36, else 0
    int nChT   = nChF + (remP ? 1 : 0);

    int tid   = threadIdx.x;
    int lane  = tid & 63;
    int l15   = lane & 15;
    int ksub  = lane >> 4;
    int wv    = tid >> 6;
    int tband = (wv >> 1) * 64;         // local t base for this wave
    int ewave = (wv & 1) * 64;

    __shared__ __align__(16) float Xs[3 * 4096];   // 3 x 16KB chunk buffers

    const char* xbase = (const char*)x;

    auto STAGE = [&](int ch, int bufOff) {
        #pragma unroll
        for (int j = 0; j < 4; ++j) {
            int pl = wv * 4 + j;
            int p  = ch * 16 + pl;
            p = (p < nPairs) ? p : (nPairs - 1);      // clamp (tail); masked later
            int c   = (p >= bw) ? 1 : 0;
            int row = (b * CC + c) * FF + f0 + (p - c * bw);
            const char* gsrc = xbase + (size_t)row * 16384 + (size_t)t0 * 8
                             + (size_t)lane * 16;
            __builtin_amdgcn_global_load_lds(
                (gu32*)gsrc, (lu32*)(Xs + bufOff + pl * 256), 16, 0, 0);
        }
    };

    const s16x8* Ab = reinterpret_cast<const s16x8*>(
        ATg + (size_t)n * CHS * (EE * 32)) + ((ewave + l15) * 4 + ksub);

    f32x4 acc[4][4];
    #pragma unroll
    for (int mi = 0; mi < 4; ++mi)
        #pragma unroll
        for (int ni = 0; ni < 4; ++ni)
            acc[mi][ni] = (f32x4){0.f, 0.f, 0.f, 0.f};
    float sA[4] = {0.f, 0.f, 0.f, 0.f};
    float qA[4] = {0.f, 0.f, 0.f, 0.f};

    STAGE(0, 0);
    STAGE(1, 4096);

    for (int ch = 0; ch < nChT; ++ch) {
        // ch's DMAs complete; ch+1's 4 (per wave) stay in flight
        if (ch + 1 < nChT) asm volatile("s_waitcnt vmcnt(4)" ::: "memory");
        else               asm volatile("s_waitcnt vmcnt(0)" ::: "memory");
        __builtin_amdgcn_s_barrier();
        __builtin_amdgcn_sched_barrier(0);

        // A fragments for this chunk (L2-hot; their auto-wait leaves new DMAs in flight)
        s16x8 a0 = Ab[ch * 512];
        s16x8 a1 = Ab[ch * 512 + 64];
        s16x8 a2 = Ab[ch * 512 + 128];
        s16x8 a3 = Ab[ch * 512 + 192];

        if (ch + 2 < nChT) STAGE(ch + 2, ((ch + 2) % 3) * 4096);

        const float2* Xp = reinterpret_cast<const float2*>(Xs + (ch % 3) * 4096);
        bool tail = (ch == nChF);       // only reachable when remP > 0

        #pragma unroll
        for (int mi = 0; mi < 4; ++mi) {
            float2 vv[4];
            #pragma unroll
            for (int j = 0; j < 4; ++j)
                vv[j] = Xp[(4 * ksub + j) * 128 + tband + mi * 16 + l15];
            if (tail) {
                #pragma unroll
                for (int j = 0; j < 4; ++j)
                    if (4 * ksub + j >= remP) vv[j] = make_float2(0.f, 0.f);
            }
            float s = 0.f, q = 0.f;
            union { s16x8 v; __hip_bfloat162 h[4]; } afu;
            #pragma unroll
            for (int j = 0; j < 4; ++j) {
                s += vv[j].x + vv[j].y;
                q = fmaf(vv[j].x, vv[j].x, q);
                q = fmaf(vv[j].y, vv[j].y, q);
                afu.h[j] = __float22bfloat162_rn(make_float2(vv[j].x, vv[j].y));
            }
            sA[mi] += s;
            qA[mi] += q;
            s16x8 af = afu.v;
            acc[mi][0] = __builtin_amdgcn_mfma_f32_16x16x32_bf16(af, a0, acc[mi][0], 0, 0, 0);
            acc[mi][1] = __builtin_amdgcn_mfma_f32_16x16x32_bf16(af, a1, acc[mi][1], 0, 0, 0);
            acc[mi][2] = __builtin_amdgcn_mfma_f32_16x16x32_bf16(af, a2, acc[mi][2], 0, 0, 0);
            acc[mi][3] = __builtin_amdgcn_mfma_f32_16x16x32_bf16(af, a3, acc[mi][3], 0, 0, 0);
        }
    }

    // ---- stats finalize: reduce over k-groups (lane bits 4,5), broadcast
    float inv = 1.f / (float)Deff;
    float mrow[4][4], rrow[4][4];
    #pragma unroll
    for (int mi = 0; mi < 4; ++mi) {
        float s = sA[mi], q = qA[mi];
        s += __shfl_xor(s, 16); s += __shfl_xor(s, 32);
        q += __shfl_xor(q, 16); q += __shfl_xor(q, 32);
        float mean = s * inv;
        float var  = fmaf(q, inv, -mean * mean);
        float rs   = rsqrtf(var + EPSF);
        #pragma unroll
        for (int j = 0; j < 4; ++j) {
            int src = (ksub << 2) + j;
            mrow[mi][j] = __shfl(mean, src);
            rrow[mi][j] = __shfl(rs, src);
        }
    }

    // ---- epilogue: z = rs*(acc - mean*s1) + s2
    float s1r[4], s2r[4];
    #pragma unroll
    for (int ni = 0; ni < 4; ++ni) {
        int e = ewave + ni * 16 + l15;
        s1r[ni] = s1a[n * EE + e];
        s2r[ni] = s2a[n * EE + e];
    }
    size_t outRow = ((size_t)(b * NB + n)) * TT;
    #pragma unroll
    for (int mi = 0; mi < 4; ++mi) {
        #pragma unroll
        for (int j = 0; j < 4; ++j) {
            int t = t0 + tband + mi * 16 + (ksub << 2) + j;
            float m = mrow[mi][j], r = rrow[mi][j];
            float* op = out + (outRow + t) * EE + ewave + l15;
            #pragma unroll
            for (int ni = 0; ni < 4; ++ni)
                op[ni * 16] = fmaf(r, acc[mi][ni][j] - m * s1r[ni], s2r[ni]);
        }
    }
}

// ---------------------------------------------------------------------------
extern "C" void kernel_launch(void* const* d_in, const int* in_sizes, int n_in,
                              void* d_out, int out_size, void* d_ws, size_t ws_size,
                              hipStream_t stream)
{
    const float* x      = (const float*)d_in[0];
    const float* gamma  = (const float*)d_in[1];
    const float* beta   = (const float*)d_in[2];
    const float* v      = (const float*)d_in[3];
    const float* g      = (const float*)d_in[4];
    const float* bias   = (const float*)d_in[5];
    const int*   bstart = (const int*)d_in[6];
    const int*   bwidth = (const int*)d_in[7];
    float* out = (float*)d_out;

    unsigned short* ATg = (unsigned short*)d_ws;                 // 37*9*128*32 bf16
    float* s1  = (float*)(ATg + (size_t)NB * CHS * EE * 32);     // 37*128 f32
    float* s2p = s1 + NB * EE;                                   // 37*128 f32

    prep_kernel<<<NB * 16, 256, 0, stream>>>(gamma, beta, v, g, bias, bwidth, ATg, s1, s2p);
    fused_kernel<<<BB * NB * 16, 256, 0, stream>>>(x, bstart, bwidth, ATg, s1, s2p, out);
}